// Round 11
// baseline (2109.831 us; speedup 1.0000x reference)
//
#include <hip/hip_runtime.h>
#include <hip/hip_bf16.h>

#define BDIM 4
#define VDIM 20000
#define DDIM 64
#define RDIM 64
#define EDIM 200000
#define BV (BDIM*VDIM)
#define LN_EPS 1e-5f
#define NBB 400           // qkproj blocks per batch

typedef __hip_bfloat16 bf16;

__device__ __forceinline__ float ldf(const float* p, size_t i){ return p[i]; }
__device__ __forceinline__ float ldf(const bf16* p, size_t i){ return __bfloat162float(p[i]); }
__device__ __forceinline__ void stf(float* p, size_t i, float v){ p[i] = v; }
__device__ __forceinline__ void stf(bf16* p, size_t i, float v){ p[i] = __float2bfloat16(v); }

__device__ __forceinline__ float wave_sum64(float x){
  #pragma unroll
  for (int o = 32; o > 0; o >>= 1) x += __shfl_xor(x, o, 64);
  return x;
}
__device__ __forceinline__ float head_sum16(float x){
  #pragma unroll
  for (int o = 8; o > 0; o >>= 1) x += __shfl_xor(x, o, 64);
  return x;
}
__device__ __forceinline__ float dot4(float4 a, float4 b){
  return a.x*b.x + a.y*b.y + a.z*b.z + a.w*b.w;
}

// ---- diagnostic fill ----
__global__ void fill_kernel(float* __restrict__ out, float v, int n){
  int t = blockIdx.x * 256 + threadIdx.x;
  if (t < n) out[t] = v;
}

// ---- int width normalize ----
__global__ void prep_idx_kernel(const int* __restrict__ ei_raw, const int* __restrict__ hi_raw,
                                int* __restrict__ ei, int* __restrict__ hi){
  __shared__ int s64;
  if (threadIdx.x == 0){
    int z = 1;
    for (int j = 1; j < 1024; j += 2) if (ei_raw[j] != 0){ z = 0; break; }
    s64 = z;
  }
  __syncthreads();
  int is64 = s64;
  int t = blockIdx.x * 256 + threadIdx.x;
  if (t < 3*EDIM) ei[t] = is64 ? ei_raw[2*t] : ei_raw[t];
  if (t < BDIM)   hi[t] = is64 ? hi_raw[2*t] : hi_raw[t];
}

__global__ void zero_kernel(int* __restrict__ counts){
  int i = blockIdx.x * 256 + threadIdx.x;
  if (i < VDIM + 1) counts[i] = 0;
}

__global__ void count_kernel(const int* __restrict__ ei, int* __restrict__ counts){
  int e = blockIdx.x * 256 + threadIdx.x;
  if (e < EDIM){
    int dst = ei[e*3], rel = ei[e*3+1], src = ei[e*3+2];
    if ((unsigned)dst < VDIM && (unsigned)rel < RDIM && (unsigned)src < VDIM)
      atomicAdd(&counts[dst], 1);
  }
}

__global__ void scan_kernel(const int* __restrict__ counts, int* __restrict__ row_ptr, int* __restrict__ cursor){
  __shared__ int buf[256];
  int tid = threadIdx.x;
  int base = 0;
  for (int c0 = 0; c0 < VDIM; c0 += 256){
    int idx = c0 + tid;
    int val = (idx < VDIM) ? counts[idx] : 0;
    buf[tid] = val;
    __syncthreads();
    for (int off = 1; off < 256; off <<= 1){
      int t = (tid >= off) ? buf[tid - off] : 0;
      __syncthreads();
      buf[tid] += t;
      __syncthreads();
    }
    int excl = buf[tid] - val;
    if (idx < VDIM){ row_ptr[idx] = base + excl; cursor[idx] = base + excl; }
    base += buf[255];
    __syncthreads();
  }
  if (tid == 0) row_ptr[VDIM] = base;
}

__global__ void scatter_kernel(const int* __restrict__ ei, int* __restrict__ cursor,
                               int2* __restrict__ pk){
  int e = blockIdx.x * 256 + threadIdx.x;
  if (e < EDIM){
    int dst = ei[e*3], rel = ei[e*3+1], src = ei[e*3+2];
    if ((unsigned)dst < VDIM && (unsigned)rel < RDIM && (unsigned)src < VDIM){
      int p = atomicAdd(&cursor[dst], 1);
      pk[p] = make_int2(rel, src);
    }
  }
}

// ---- z projections ----
__global__ void zcalc_kernel(const float* __restrict__ z,
                             const float* __restrict__ qkzw, const float* __restrict__ qkzb,
                             const float* __restrict__ vfw,  const float* __restrict__ vfb,
                             float* __restrict__ qk_z, float* __restrict__ zr){
  int idx = blockIdx.x * 256 + threadIdx.x;
  if (idx >= 49152) return;
  int which = idx >> 14;
  int r = idx & 16383;
  int b = r >> 12;
  int j = r & 4095;
  const float* wrow; float bias; float* outp;
  if (which == 0){ wrow = qkzw + (size_t)j*DDIM; bias = qkzb[j]; outp = qk_z; }
  else { int i = which - 1; wrow = vfw + (size_t)(i*4096 + j)*DDIM; bias = vfb[i*4096 + j]; outp = zr + i*16384; }
  const float* zrow = z + (size_t)b*DDIM;
  float acc = bias;
  for (int d = 0; d < DDIM; d++) acc += zrow[d] * wrow[d];
  outp[r] = acc;
}

// ---- init qk_x: fused MLP, weights in registers ----
template<typename T>
__global__ __launch_bounds__(256) void init_qk_kernel(
    const float* __restrict__ x, const float* __restrict__ noise,
    const float* __restrict__ w1, const float* __restrict__ b1,
    const float* __restrict__ w2, const float* __restrict__ b2,
    T* __restrict__ out){
  __shared__ __align__(16) float tb[4*64];
  __shared__ __align__(16) float hb[4*64];
  int tid = threadIdx.x, lane = tid & 63, wid = tid >> 6;
  float w1a[64]; float4 w2r[16];
  #pragma unroll
  for (int i = 0; i < 64; i++) w1a[i] = w1[lane*65 + i];
  float wn = w1[lane*65 + 64];
  const float4* w2v = (const float4*)w2;
  #pragma unroll
  for (int i = 0; i < 16; i++) w2r[i] = w2v[lane*16 + i];
  float b1l = b1[lane], b2l = b2[lane];
  const float4* tbv = (const float4*)tb;
  const float4* hbv = (const float4*)hb;
  for (int r0 = blockIdx.x*4; r0 < BV; r0 += gridDim.x*4){
    int row = r0 + wid;
    size_t rb = (size_t)row*64;
    tb[wid*64+lane] = x[rb+lane];
    float nz = noise[row];
    __syncthreads();
    float h = b1l + wn * nz;
    #pragma unroll
    for (int i4 = 0; i4 < 16; i4++){
      float4 t = tbv[wid*16 + i4];
      h += w1a[i4*4+0]*t.x + w1a[i4*4+1]*t.y + w1a[i4*4+2]*t.z + w1a[i4*4+3]*t.w;
    }
    hb[wid*64+lane] = fmaxf(h, 0.f);
    __syncthreads();
    float y = b2l;
    #pragma unroll
    for (int i4 = 0; i4 < 16; i4++) y += dot4(w2r[i4], hbv[wid*16 + i4]);
    stf(out, rb+lane, y);
  }
}

// ---- init v_x ----
template<typename T>
__global__ __launch_bounds__(256) void init_v_kernel(
    const float* __restrict__ x, const int* __restrict__ h_index,
    const float* __restrict__ w1, const float* __restrict__ b1,
    const float* __restrict__ w2, const float* __restrict__ b2,
    T* __restrict__ out){
  __shared__ __align__(16) float tb[4*64];
  __shared__ __align__(16) float hb[4*64];
  int tid = threadIdx.x, lane = tid & 63, wid = tid >> 6;
  float4 w1r[16], w2r[16];
  const float4* w1v = (const float4*)w1;     // [64][128]
  const float4* w2v = (const float4*)w2;
  #pragma unroll
  for (int i = 0; i < 16; i++){ w1r[i] = w1v[lane*32 + i]; w2r[i] = w2v[lane*16 + i]; }
  float rsv = 0.f;
  #pragma unroll
  for (int i = 0; i < 16; i++){ float4 t = w1v[lane*32 + 16 + i]; rsv += t.x+t.y+t.z+t.w; }
  float b1l = b1[lane], b2l = b2[lane];
  int h0 = h_index[0], h1 = h_index[1], h2 = h_index[2], h3 = h_index[3];
  const float4* tbv = (const float4*)tb;
  const float4* hbv = (const float4*)hb;
  for (int r0 = blockIdx.x*4; r0 < BV; r0 += gridDim.x*4){
    int row = r0 + wid;
    int b = row / VDIM, v = row - b*VDIM;
    int hv = (b == 0) ? h0 : (b == 1) ? h1 : (b == 2) ? h2 : h3;
    size_t rb = (size_t)row*64;
    tb[wid*64+lane] = x[rb+lane];
    __syncthreads();
    float h = b1l + ((v == hv) ? rsv : 0.f);
    #pragma unroll
    for (int i4 = 0; i4 < 16; i4++) h += dot4(w1r[i4], tbv[wid*16 + i4]);
    hb[wid*64+lane] = fmaxf(h, 0.f);
    __syncthreads();
    float y = b2l;
    #pragma unroll
    for (int i4 = 0; i4 < 16; i4++) y += dot4(w2r[i4], hbv[wid*16 + i4]);
    stf(out, rb+lane, y);
  }
}

// ---- FUSED loop iteration: rspmm gather + axpy + MLP + LN + residual ----
// block = vertex v, wave wid = batch b, lane = feature d.
// Reads Xold (gather + residual), writes Xnew. Ping-pong between calls.
template<typename T>
__global__ __launch_bounds__(256) void fused_loop(
    const int* __restrict__ row_ptr, const int2* __restrict__ pk,
    const float* __restrict__ zrel,
    const T* __restrict__ Xold, T* __restrict__ Xnew,
    const float* __restrict__ alpha, const float* __restrict__ w1, const float* __restrict__ b1,
    const float* __restrict__ w2, const float* __restrict__ b2,
    const float* __restrict__ ng, const float* __restrict__ nb){
  __shared__ __align__(16) float tb[4*64];
  __shared__ __align__(16) float hb[4*64];
  int tid = threadIdx.x, lane = tid & 63, wid = tid >> 6;
  float4 w1r[16], w2r[16];
  const float4* w1v = (const float4*)w1;
  const float4* w2v = (const float4*)w2;
  #pragma unroll
  for (int i = 0; i < 16; i++){ w1r[i] = w1v[lane*16 + i]; w2r[i] = w2v[lane*16 + i]; }
  float all = alpha[lane], b1l = b1[lane], b2l = b2[lane];
  float ngl = ng[lane], nbl = nb[lane];
  const float4* tbv = (const float4*)tb;
  const float4* hbv = (const float4*)hb;

  int v = blockIdx.x;
  int s = row_ptr[v], e = row_ptr[v+1];
  const float* zb = zrel + wid*RDIM*DDIM + lane;
  size_t xb = (size_t)wid*VDIM*64 + lane;
  float acc = 0.f;
  for (int i = s; i < e; i++){
    int2 ed = pk[i];
    acc += zb[ed.x*64] * ldf(Xold, xb + (size_t)ed.y*64);
  }
  size_t rb = ((size_t)wid*VDIM + v)*64;
  float xs = ldf(Xold, rb+lane);
  tb[wid*64+lane] = acc + all * xs;
  __syncthreads();
  float h = b1l;
  #pragma unroll
  for (int i4 = 0; i4 < 16; i4++) h += dot4(w1r[i4], tbv[wid*16 + i4]);
  hb[wid*64+lane] = fmaxf(h, 0.f);
  __syncthreads();
  float y = b2l;
  #pragma unroll
  for (int i4 = 0; i4 < 16; i4++) y += dot4(w2r[i4], hbv[wid*16 + i4]);
  float mu = wave_sum64(y) * (1.f/64.f);
  float c = y - mu;
  float var = wave_sum64(c*c) * (1.f/64.f);
  stf(Xnew, rb+lane, c * rsqrtf(var + LN_EPS) * ngl + nbl + xs);
}

// ---- qkproj: weights in regs, prefetch, per-block partial reduction ----
template<typename T>
__global__ __launch_bounds__(256) void qkproj_kernel(
    T* __restrict__ Xqk, const T* __restrict__ Xv,
    const float* __restrict__ w, const float* __restrict__ bias,
    float* __restrict__ partial){
  __shared__ __align__(16) float tb[4*64];
  __shared__ __align__(16) float red[4*1152];
  int tid = threadIdx.x, lane = tid & 63, wid = tid >> 6;
  float4 wq[16], wk[16];
  const float4* wv = (const float4*)w;
  #pragma unroll
  for (int i = 0; i < 16; i++){ wq[i] = wv[lane*16 + i]; wk[i] = wv[(64+lane)*16 + i]; }
  float bq = bias[lane], bk = bias[64+lane];
  int b = blockIdx.x / NBB, blk = blockIdx.x % NBB;
  float kv[16];
  #pragma unroll
  for (int i = 0; i < 16; i++) kv[i] = 0.f;
  float ks = 0.f, vs = 0.f;
  const float4* tbv = (const float4*)tb;

  size_t rowc = ((size_t)b*VDIM + blk*4 + wid)*64;
  float cur = ldf(Xqk, rowc+lane);
  float vvc = ldf(Xv, rowc+lane);
  for (int v0 = blk*4; v0 < VDIM; v0 += NBB*4){
    tb[wid*64+lane] = cur;
    __syncthreads();
    // prefetch next rows while computing
    int v0n = v0 + NBB*4;
    size_t rown = ((size_t)b*VDIM + v0n + wid)*64;
    float nxt = 0.f, vvn = 0.f;
    if (v0n < VDIM){ nxt = ldf(Xqk, rown+lane); vvn = ldf(Xv, rown+lane); }
    float q = bq, k = bk;
    #pragma unroll
    for (int i4 = 0; i4 < 16; i4++){
      float4 t = tbv[wid*16 + i4];
      q += dot4(wq[i4], t);
      k += dot4(wk[i4], t);
    }
    float qn2 = head_sum16(q*q);
    float kn2 = head_sum16(k*k);
    q = q / fmaxf(sqrtf(qn2), 1e-12f);
    k = k / fmaxf(sqrtf(kn2), 1e-12f);
    stf(Xqk, rowc+lane, q);            // qn in place
    ks += k; vs += vvc;
    int base = lane & 48;              // h*16
    #pragma unroll
    for (int dl = 0; dl < 16; dl++){
      float vdl = __shfl(vvc, base + dl, 64);
      kv[dl] += k * vdl;
    }
    __syncthreads();
    cur = nxt; vvc = vvn; rowc = rown;
  }
  float* rw = red + wid*1152;
  #pragma unroll
  for (int dl = 0; dl < 16; dl++) rw[lane*16 + dl] = kv[dl];
  rw[1024 + lane] = ks;
  rw[1088 + lane] = vs;
  __syncthreads();
  float* P = partial + (size_t)blockIdx.x*1152;
  for (int j = tid; j < 1152; j += 256)
    P[j] = red[j] + red[1152+j] + red[2304+j] + red[3456+j];
}

// ---- reduce qkproj partials ----
__global__ void qkred_kernel(const float* __restrict__ partial,
                             float* __restrict__ kvs, float* __restrict__ ksum, float* __restrict__ vsum){
  int b = blockIdx.x / 5, ch = blockIdx.x % 5;
  int j = ch*256 + threadIdx.x;
  if (j >= 1152) return;
  const float* P = partial + (size_t)b*NBB*1152;
  float s = 0.f;
  for (int t = 0; t < NBB; t++) s += P[(size_t)t*1152 + j];
  if (j < 1024)      kvs[b*1024 + j] = s;
  else if (j < 1088) ksum[b*64 + (j-1024)] = s;
  else               vsum[b*64 + (j-1088)] = s;
}

// ---- FUSED attention finalize + LN + FFN + LN -> fp32 out ----
template<typename T>
__global__ __launch_bounds__(256) void attn_ffn_kernel(
    const float* __restrict__ x, const T* __restrict__ A, const T* __restrict__ Xv,
    const float* __restrict__ kvs, const float* __restrict__ ksum, const float* __restrict__ vsum,
    const float* __restrict__ g1, const float* __restrict__ bg1,
    const float* __restrict__ w1, const float* __restrict__ b1,
    const float* __restrict__ w2, const float* __restrict__ b2,
    const float* __restrict__ g2, const float* __restrict__ bg2,
    float* __restrict__ out){
  __shared__ float kvss[4096], kss[256], vss[256];
  __shared__ __align__(16) float tb[4*64];
  __shared__ __align__(16) float hb[4*64];
  int tid = threadIdx.x, lane = tid & 63, wid = tid >> 6;
  for (int i = tid; i < 4096; i += 256) kvss[i] = kvs[i];
  kss[tid] = ksum[tid];
  vss[tid] = vsum[tid];
  float4 w1r[16], w2r[16];
  const float4* w1v = (const float4*)w1;
  const float4* w2v = (const float4*)w2;
  #pragma unroll
  for (int i = 0; i < 16; i++){ w1r[i] = w1v[lane*16 + i]; w2r[i] = w2v[lane*16 + i]; }
  float g1l = g1[lane], bg1l = bg1[lane], b1l = b1[lane], b2l = b2[lane];
  float g2l = g2[lane], bg2l = bg2[lane];
  const float4* tbv = (const float4*)tb;
  const float4* hbv = (const float4*)hb;
  __syncthreads();
  int h16 = lane & 48, dl = lane & 15;
  for (int r0 = blockIdx.x*4; r0 < BV; r0 += gridDim.x*4){
    int row = r0 + wid;
    int b = row / VDIM;
    size_t rb = (size_t)row*64;
    float qv = ldf(A, rb+lane);
    float vv = ldf(Xv, rb+lane);
    float num = vss[b*64+lane] + vv * (float)VDIM;
    float den = 2.0f * (float)VDIM;
    int kbase = b*1024 + h16*16 + dl;
    int ksbase = b*64 + h16;
    #pragma unroll
    for (int j = 0; j < 16; j++){
      float qj = __shfl(qv, h16 + j, 64);
      num += qj * kvss[kbase + j*16];
      den += qj * kss[ksbase + j];
    }
    float y = x[rb+lane] + num / den;
    float mu = wave_sum64(y) * (1.f/64.f);
    float c = y - mu;
    float var = wave_sum64(c*c) * (1.f/64.f);
    float x1 = c * rsqrtf(var + LN_EPS) * g1l + bg1l;    // post-attn LN
    tb[wid*64+lane] = x1;
    __syncthreads();
    float h = b1l;
    #pragma unroll
    for (int i4 = 0; i4 < 16; i4++) h += dot4(w1r[i4], tbv[wid*16 + i4]);
    hb[wid*64+lane] = fmaxf(h, 0.f);
    __syncthreads();
    float y2 = b2l;
    #pragma unroll
    for (int i4 = 0; i4 < 16; i4++) y2 += dot4(w2r[i4], hbv[wid*16 + i4]);
    float t = x1 + y2;
    float mu2 = wave_sum64(t) * (1.f/64.f);
    float c2 = t - mu2;
    float var2 = wave_sum64(c2*c2) * (1.f/64.f);
    out[rb+lane] = c2 * rsqrtf(var2 + LN_EPS) * g2l + bg2l;
    __syncthreads();
  }
}

// ================= host side =================
static const int DICT_SIZES[42] = {
  5120000,256,256,80000,262144,4096,4160,64,4096,64,
  8192,64,4096,64,8192,128,8192,128,8192,128,
  128,128,128,524288,8192,8192,128,8192,128,128,
  128,128,4096,64,4096,64,64,64,64,64,
  4,600000};

template<typename T>
static void run_pipeline(const float* const* N, const int* hi,
                         const int* row_ptr, const int2* pk,
                         float* qk_z, float* zr, float* kvs, float* part,
                         T* P, T* A, T* B, float* outp, hipStream_t stream){
  float* ksum = kvs + 4096;
  float* vsum = kvs + 4352;
  const int GM = 2000;

  zcalc_kernel<<<192, 256, 0, stream>>>(N[1], N[4], N[5], N[23], N[24], qk_z, zr);

  // ---- qk stream: A -> P -> A ----
  init_qk_kernel<T><<<GM, 256, 0, stream>>>(N[0], N[3], N[6], N[7], N[8], N[9], A);
  fused_loop<T><<<VDIM, 256, 0, stream>>>(row_ptr, pk, qk_z, A, P,
      N[20], N[16], N[17], N[18], N[19], N[21], N[22]);
  fused_loop<T><<<VDIM, 256, 0, stream>>>(row_ptr, pk, qk_z, P, A,
      N[20]+64, N[16]+4096, N[17]+64, N[18]+4096, N[19]+64, N[21]+64, N[22]+64);
  // ---- v stream: B -> P -> B ----
  init_v_kernel<T><<<GM, 256, 0, stream>>>(N[0], hi, N[10], N[11], N[12], N[13], B);
  fused_loop<T><<<VDIM, 256, 0, stream>>>(row_ptr, pk, zr, B, P,
      N[29], N[25], N[26], N[27], N[28], N[30], N[31]);
  fused_loop<T><<<VDIM, 256, 0, stream>>>(row_ptr, pk, zr+16384, P, B,
      N[29]+64, N[25]+4096, N[26]+64, N[27]+4096, N[28]+64, N[30]+64, N[31]+64);
  // ---- attention ----
  qkproj_kernel<T><<<BDIM*NBB, 256, 0, stream>>>(A, B, N[14], N[15], part);
  qkred_kernel<<<20, 256, 0, stream>>>(part, kvs, ksum, vsum);
  attn_ffn_kernel<T><<<GM, 256, 0, stream>>>(N[0], A, B, kvs, ksum, vsum,
      N[36], N[37], N[32], N[33], N[34], N[35], N[38], N[39], outp);
}

extern "C" void kernel_launch(void* const* d_in, const int* in_sizes, int n_in,
                              void* d_out, int out_size, void* d_ws, size_t ws_size,
                              hipStream_t stream){
  float* outp = (float*)d_out;
  const int GOUT = (out_size + 255) / 256;

  if (n_in != 42){
    fill_kernel<<<GOUT, 256, 0, stream>>>(outp, 2000.0f + (float)n_in, out_size);
    return;
  }
  auto sz_ok = [&](int s, int e)->bool{
    if (s == e) return true;
    if ((e == 4 || e == 600000) && s == 2*e) return true;
    return false;
  };
  int bad = -1;
  for (int i = 0; i < 42 && bad < 0; i++)
    if (!sz_ok(in_sizes[i], DICT_SIZES[i])) bad = i;
  if (bad >= 0){
    fill_kernel<<<GOUT, 256, 0, stream>>>(outp, 1000.0f + (float)bad, out_size);
    return;
  }

  const float* N[40];
  for (int i = 0; i < 40; i++) N[i] = (const float*)d_in[i];
  const int* hi_raw = (const int*)d_in[40];
  const int* ei_raw = (const int*)d_in[41];

  char* p = (char*)d_ws;
  auto alloc = [&](size_t bytes)->char*{ char* r = p; p += (bytes + 255) / 256 * 256; return r; };
  int* ei      = (int*)alloc((size_t)3*EDIM*4);
  int* hi      = (int*)alloc(256);
  int* counts  = (int*)alloc((VDIM+1)*4);
  int* row_ptr = (int*)alloc((VDIM+1)*4);
  int* cursor  = (int*)alloc((VDIM+1)*4);
  int2* pk     = (int2*)alloc((size_t)EDIM*8);
  float* qk_z  = (float*)alloc(16384u*4);
  float* zr    = (float*)alloc(32768u*4);
  float* kvs   = (float*)alloc(4608u*4);
  float* part  = (float*)alloc((size_t)BDIM*NBB*1152*4);
  size_t fixed = (size_t)(p - (char*)d_ws);
  bool f32ok = ws_size >= fixed + 3*(size_t)BV*64*4 + 1024;

  prep_idx_kernel<<<(3*EDIM+255)/256, 256, 0, stream>>>(ei_raw, hi_raw, ei, hi);
  zero_kernel<<<(VDIM+256)/256, 256, 0, stream>>>(counts);
  count_kernel<<<(EDIM+255)/256, 256, 0, stream>>>(ei, counts);
  scan_kernel<<<1, 256, 0, stream>>>(counts, row_ptr, cursor);
  scatter_kernel<<<(EDIM+255)/256, 256, 0, stream>>>(ei, cursor, pk);

  if (f32ok){
    float* P = (float*)alloc((size_t)BV*64*4);
    float* A = (float*)alloc((size_t)BV*64*4);
    float* B = (float*)alloc((size_t)BV*64*4);
    run_pipeline<float>(N, hi, row_ptr, pk, qk_z, zr, kvs, part, P, A, B, outp, stream);
  } else {
    bf16* P = (bf16*)alloc((size_t)BV*64*2);
    bf16* A = (bf16*)alloc((size_t)BV*64*2);
    bf16* B = (bf16*)alloc((size_t)BV*64*2);
    run_pipeline<bf16>(N, hi, row_ptr, pk, qk_z, zr, kvs, part, P, A, B, outp, stream);
  }
}

// Round 12
// 1956.384 us; speedup vs baseline: 1.0784x; 1.0784x over previous
//
#include <hip/hip_runtime.h>
#include <hip/hip_bf16.h>

#define BDIM 4
#define VDIM 20000
#define DDIM 64
#define RDIM 64
#define EDIM 200000
#define BV (BDIM*VDIM)
#define LN_EPS 1e-5f
#define NBB 400           // qkproj blocks per batch
#define VPB 16            // vertices per fused_loop block

typedef __hip_bfloat16 bf16;

__device__ __forceinline__ float ldf(const float* p, size_t i){ return p[i]; }
__device__ __forceinline__ float ldf(const bf16* p, size_t i){ return __bfloat162float(p[i]); }
__device__ __forceinline__ void stf(float* p, size_t i, float v){ p[i] = v; }
__device__ __forceinline__ void stf(bf16* p, size_t i, float v){ p[i] = __float2bfloat16(v); }

__device__ __forceinline__ float wave_sum64(float x){
  #pragma unroll
  for (int o = 32; o > 0; o >>= 1) x += __shfl_xor(x, o, 64);
  return x;
}
__device__ __forceinline__ float head_sum16(float x){
  #pragma unroll
  for (int o = 8; o > 0; o >>= 1) x += __shfl_xor(x, o, 64);
  return x;
}
__device__ __forceinline__ float dot4(float4 a, float4 b){
  return a.x*b.x + a.y*b.y + a.z*b.z + a.w*b.w;
}

// ---- diagnostic fill ----
__global__ void fill_kernel(float* __restrict__ out, float v, int n){
  int t = blockIdx.x * 256 + threadIdx.x;
  if (t < n) out[t] = v;
}

// ---- int width normalize ----
__global__ void prep_idx_kernel(const int* __restrict__ ei_raw, const int* __restrict__ hi_raw,
                                int* __restrict__ ei, int* __restrict__ hi){
  __shared__ int s64;
  if (threadIdx.x == 0){
    int z = 1;
    for (int j = 1; j < 1024; j += 2) if (ei_raw[j] != 0){ z = 0; break; }
    s64 = z;
  }
  __syncthreads();
  int is64 = s64;
  int t = blockIdx.x * 256 + threadIdx.x;
  if (t < 3*EDIM) ei[t] = is64 ? ei_raw[2*t] : ei_raw[t];
  if (t < BDIM)   hi[t] = is64 ? hi_raw[2*t] : hi_raw[t];
}

__global__ void zero_kernel(int* __restrict__ counts){
  int i = blockIdx.x * 256 + threadIdx.x;
  if (i < VDIM + 1) counts[i] = 0;
}

__global__ void count_kernel(const int* __restrict__ ei, int* __restrict__ counts){
  int e = blockIdx.x * 256 + threadIdx.x;
  if (e < EDIM){
    int dst = ei[e*3], rel = ei[e*3+1], src = ei[e*3+2];
    if ((unsigned)dst < VDIM && (unsigned)rel < RDIM && (unsigned)src < VDIM)
      atomicAdd(&counts[dst], 1);
  }
}

__global__ void scan_kernel(const int* __restrict__ counts, int* __restrict__ row_ptr, int* __restrict__ cursor){
  __shared__ int buf[256];
  int tid = threadIdx.x;
  int base = 0;
  for (int c0 = 0; c0 < VDIM; c0 += 256){
    int idx = c0 + tid;
    int val = (idx < VDIM) ? counts[idx] : 0;
    buf[tid] = val;
    __syncthreads();
    for (int off = 1; off < 256; off <<= 1){
      int t = (tid >= off) ? buf[tid - off] : 0;
      __syncthreads();
      buf[tid] += t;
      __syncthreads();
    }
    int excl = buf[tid] - val;
    if (idx < VDIM){ row_ptr[idx] = base + excl; cursor[idx] = base + excl; }
    base += buf[255];
    __syncthreads();
  }
  if (tid == 0) row_ptr[VDIM] = base;
}

__global__ void scatter_kernel(const int* __restrict__ ei, int* __restrict__ cursor,
                               int2* __restrict__ pk){
  int e = blockIdx.x * 256 + threadIdx.x;
  if (e < EDIM){
    int dst = ei[e*3], rel = ei[e*3+1], src = ei[e*3+2];
    if ((unsigned)dst < VDIM && (unsigned)rel < RDIM && (unsigned)src < VDIM){
      int p = atomicAdd(&cursor[dst], 1);
      pk[p] = make_int2(rel, src);
    }
  }
}

// ---- z projections ----
__global__ void zcalc_kernel(const float* __restrict__ z,
                             const float* __restrict__ qkzw, const float* __restrict__ qkzb,
                             const float* __restrict__ vfw,  const float* __restrict__ vfb,
                             float* __restrict__ qk_z, float* __restrict__ zr){
  int idx = blockIdx.x * 256 + threadIdx.x;
  if (idx >= 49152) return;
  int which = idx >> 14;
  int r = idx & 16383;
  int b = r >> 12;
  int j = r & 4095;
  const float* wrow; float bias; float* outp;
  if (which == 0){ wrow = qkzw + (size_t)j*DDIM; bias = qkzb[j]; outp = qk_z; }
  else { int i = which - 1; wrow = vfw + (size_t)(i*4096 + j)*DDIM; bias = vfb[i*4096 + j]; outp = zr + i*16384; }
  const float* zrow = z + (size_t)b*DDIM;
  float acc = bias;
  for (int d = 0; d < DDIM; d++) acc += zrow[d] * wrow[d];
  outp[r] = acc;
}

// ---- init qk_x ----
template<typename T>
__global__ __launch_bounds__(256) void init_qk_kernel(
    const float* __restrict__ x, const float* __restrict__ noise,
    const float* __restrict__ w1, const float* __restrict__ b1,
    const float* __restrict__ w2, const float* __restrict__ b2,
    T* __restrict__ out){
  __shared__ __align__(16) float tb[4*64];
  __shared__ __align__(16) float hb[4*64];
  int tid = threadIdx.x, lane = tid & 63, wid = tid >> 6;
  float w1a[64]; float4 w2r[16];
  #pragma unroll
  for (int i = 0; i < 64; i++) w1a[i] = w1[lane*65 + i];
  float wn = w1[lane*65 + 64];
  const float4* w2v = (const float4*)w2;
  #pragma unroll
  for (int i = 0; i < 16; i++) w2r[i] = w2v[lane*16 + i];
  float b1l = b1[lane], b2l = b2[lane];
  const float4* tbv = (const float4*)tb;
  const float4* hbv = (const float4*)hb;
  for (int r0 = blockIdx.x*4; r0 < BV; r0 += gridDim.x*4){
    int row = r0 + wid;
    size_t rb = (size_t)row*64;
    tb[wid*64+lane] = x[rb+lane];
    float nz = noise[row];
    __syncthreads();
    float h = b1l + wn * nz;
    #pragma unroll
    for (int i4 = 0; i4 < 16; i4++){
      float4 t = tbv[wid*16 + i4];
      h += w1a[i4*4+0]*t.x + w1a[i4*4+1]*t.y + w1a[i4*4+2]*t.z + w1a[i4*4+3]*t.w;
    }
    hb[wid*64+lane] = fmaxf(h, 0.f);
    __syncthreads();
    float y = b2l;
    #pragma unroll
    for (int i4 = 0; i4 < 16; i4++) y += dot4(w2r[i4], hbv[wid*16 + i4]);
    stf(out, rb+lane, y);
    __syncthreads();
  }
}

// ---- init v_x ----
template<typename T>
__global__ __launch_bounds__(256) void init_v_kernel(
    const float* __restrict__ x, const int* __restrict__ h_index,
    const float* __restrict__ w1, const float* __restrict__ b1,
    const float* __restrict__ w2, const float* __restrict__ b2,
    T* __restrict__ out){
  __shared__ __align__(16) float tb[4*64];
  __shared__ __align__(16) float hb[4*64];
  int tid = threadIdx.x, lane = tid & 63, wid = tid >> 6;
  float4 w1r[16], w2r[16];
  const float4* w1v = (const float4*)w1;     // [64][128]
  const float4* w2v = (const float4*)w2;
  #pragma unroll
  for (int i = 0; i < 16; i++){ w1r[i] = w1v[lane*32 + i]; w2r[i] = w2v[lane*16 + i]; }
  float rsv = 0.f;
  #pragma unroll
  for (int i = 0; i < 16; i++){ float4 t = w1v[lane*32 + 16 + i]; rsv += t.x+t.y+t.z+t.w; }
  float b1l = b1[lane], b2l = b2[lane];
  int h0 = h_index[0], h1 = h_index[1], h2 = h_index[2], h3 = h_index[3];
  const float4* tbv = (const float4*)tb;
  const float4* hbv = (const float4*)hb;
  for (int r0 = blockIdx.x*4; r0 < BV; r0 += gridDim.x*4){
    int row = r0 + wid;
    int b = row / VDIM, v = row - b*VDIM;
    int hv = (b == 0) ? h0 : (b == 1) ? h1 : (b == 2) ? h2 : h3;
    size_t rb = (size_t)row*64;
    tb[wid*64+lane] = x[rb+lane];
    __syncthreads();
    float h = b1l + ((v == hv) ? rsv : 0.f);
    #pragma unroll
    for (int i4 = 0; i4 < 16; i4++) h += dot4(w1r[i4], tbv[wid*16 + i4]);
    hb[wid*64+lane] = fmaxf(h, 0.f);
    __syncthreads();
    float y = b2l;
    #pragma unroll
    for (int i4 = 0; i4 < 16; i4++) y += dot4(w2r[i4], hbv[wid*16 + i4]);
    stf(out, rb+lane, y);
    __syncthreads();
  }
}

// ---- FUSED loop iteration v2: VPB vertices/block, batch-pinned, zrel in LDS ----
// block: batch b = blockIdx&3 (XCD affinity), vertex group g = blockIdx>>2.
// wave wid handles vertex g*VPB + vi + wid; lane = feature.
template<typename T>
__global__ __launch_bounds__(256) void fused_loop(
    const int* __restrict__ row_ptr, const int2* __restrict__ pk,
    const float* __restrict__ zrel,
    const T* __restrict__ Xold, T* __restrict__ Xnew,
    const float* __restrict__ alpha, const float* __restrict__ w1, const float* __restrict__ b1,
    const float* __restrict__ w2, const float* __restrict__ b2,
    const float* __restrict__ ng, const float* __restrict__ nb){
  __shared__ __align__(16) float zs[RDIM*DDIM];   // 16 KB: this batch's zrel
  __shared__ __align__(16) float tb[4*64];
  __shared__ __align__(16) float hb[4*64];
  int tid = threadIdx.x, lane = tid & 63, wid = tid >> 6;
  int b = blockIdx.x & 3;
  int g = blockIdx.x >> 2;
  const float* zb = zrel + b*RDIM*DDIM;
  for (int i = tid; i < RDIM*DDIM; i += 256) zs[i] = zb[i];
  float4 w1r[16], w2r[16];
  const float4* w1v = (const float4*)w1;
  const float4* w2v = (const float4*)w2;
  #pragma unroll
  for (int i = 0; i < 16; i++){ w1r[i] = w1v[lane*16 + i]; w2r[i] = w2v[lane*16 + i]; }
  float all = alpha[lane], b1l = b1[lane], b2l = b2[lane];
  float ngl = ng[lane], nbl = nb[lane];
  const float4* tbv = (const float4*)tb;
  const float4* hbv = (const float4*)hb;
  size_t xb = (size_t)b*VDIM*64;
  __syncthreads();
  for (int vi = 0; vi < VPB; vi += 4){
    int v = g*VPB + vi + wid;
    float acc = 0.f, xs = 0.f;
    if (v < VDIM){
      int s = row_ptr[v], e = row_ptr[v+1];
      for (int i = s; i < e; i++){
        int2 ed = pk[i];
        acc += zs[ed.x*64 + lane] * ldf(Xold, xb + (size_t)ed.y*64 + lane);
      }
      xs = ldf(Xold, xb + (size_t)v*64 + lane);
    }
    tb[wid*64+lane] = acc + all * xs;
    __syncthreads();
    float h = b1l;
    #pragma unroll
    for (int i4 = 0; i4 < 16; i4++) h += dot4(w1r[i4], tbv[wid*16 + i4]);
    hb[wid*64+lane] = fmaxf(h, 0.f);
    __syncthreads();
    float y = b2l;
    #pragma unroll
    for (int i4 = 0; i4 < 16; i4++) y += dot4(w2r[i4], hbv[wid*16 + i4]);
    float mu = wave_sum64(y) * (1.f/64.f);
    float c = y - mu;
    float var = wave_sum64(c*c) * (1.f/64.f);
    if (v < VDIM)
      stf(Xnew, xb + (size_t)v*64 + lane, c * rsqrtf(var + LN_EPS) * ngl + nbl + xs);
    __syncthreads();
  }
}

// ---- qkproj: weights in regs, prefetch, per-block partial reduction ----
template<typename T>
__global__ __launch_bounds__(256) void qkproj_kernel(
    T* __restrict__ Xqk, const T* __restrict__ Xv,
    const float* __restrict__ w, const float* __restrict__ bias,
    float* __restrict__ partial){
  __shared__ __align__(16) float tb[4*64];
  __shared__ __align__(16) float red[4*1152];
  int tid = threadIdx.x, lane = tid & 63, wid = tid >> 6;
  float4 wq[16], wk[16];
  const float4* wv = (const float4*)w;
  #pragma unroll
  for (int i = 0; i < 16; i++){ wq[i] = wv[lane*16 + i]; wk[i] = wv[(64+lane)*16 + i]; }
  float bq = bias[lane], bk = bias[64+lane];
  int b = blockIdx.x / NBB, blk = blockIdx.x % NBB;
  float kv[16];
  #pragma unroll
  for (int i = 0; i < 16; i++) kv[i] = 0.f;
  float ks = 0.f, vs = 0.f;
  const float4* tbv = (const float4*)tb;

  size_t rowc = ((size_t)b*VDIM + blk*4 + wid)*64;
  float cur = ldf(Xqk, rowc+lane);
  float vvc = ldf(Xv, rowc+lane);
  for (int v0 = blk*4; v0 < VDIM; v0 += NBB*4){
    tb[wid*64+lane] = cur;
    __syncthreads();
    int v0n = v0 + NBB*4;
    size_t rown = ((size_t)b*VDIM + v0n + wid)*64;
    float nxt = 0.f, vvn = 0.f;
    if (v0n < VDIM){ nxt = ldf(Xqk, rown+lane); vvn = ldf(Xv, rown+lane); }
    float q = bq, k = bk;
    #pragma unroll
    for (int i4 = 0; i4 < 16; i4++){
      float4 t = tbv[wid*16 + i4];
      q += dot4(wq[i4], t);
      k += dot4(wk[i4], t);
    }
    float qn2 = head_sum16(q*q);
    float kn2 = head_sum16(k*k);
    q = q / fmaxf(sqrtf(qn2), 1e-12f);
    k = k / fmaxf(sqrtf(kn2), 1e-12f);
    stf(Xqk, rowc+lane, q);            // qn in place
    ks += k; vs += vvc;
    int base = lane & 48;              // h*16
    #pragma unroll
    for (int dl = 0; dl < 16; dl++){
      float vdl = __shfl(vvc, base + dl, 64);
      kv[dl] += k * vdl;
    }
    __syncthreads();
    cur = nxt; vvc = vvn; rowc = rown;
  }
  float* rw = red + wid*1152;
  #pragma unroll
  for (int dl = 0; dl < 16; dl++) rw[lane*16 + dl] = kv[dl];
  rw[1024 + lane] = ks;
  rw[1088 + lane] = vs;
  __syncthreads();
  float* P = partial + (size_t)blockIdx.x*1152;
  for (int j = tid; j < 1152; j += 256)
    P[j] = red[j] + red[1152+j] + red[2304+j] + red[3456+j];
}

// ---- reduce qkproj partials ----
__global__ void qkred_kernel(const float* __restrict__ partial,
                             float* __restrict__ kvs, float* __restrict__ ksum, float* __restrict__ vsum){
  int b = blockIdx.x / 5, ch = blockIdx.x % 5;
  int j = ch*256 + threadIdx.x;
  if (j >= 1152) return;
  const float* P = partial + (size_t)b*NBB*1152;
  float s = 0.f;
  for (int t = 0; t < NBB; t++) s += P[(size_t)t*1152 + j];
  if (j < 1024)      kvs[b*1024 + j] = s;
  else if (j < 1088) ksum[b*64 + (j-1024)] = s;
  else               vsum[b*64 + (j-1088)] = s;
}

// ---- FUSED attention finalize + LN + FFN + LN -> fp32 out ----
template<typename T>
__global__ __launch_bounds__(256) void attn_ffn_kernel(
    const float* __restrict__ x, const T* __restrict__ A, const T* __restrict__ Xv,
    const float* __restrict__ kvs, const float* __restrict__ ksum, const float* __restrict__ vsum,
    const float* __restrict__ g1, const float* __restrict__ bg1,
    const float* __restrict__ w1, const float* __restrict__ b1,
    const float* __restrict__ w2, const float* __restrict__ b2,
    const float* __restrict__ g2, const float* __restrict__ bg2,
    float* __restrict__ out){
  __shared__ float kvss[4*64*17];          // stride 17: bank-conflict-free
  __shared__ float kss[256], vss[256];
  __shared__ __align__(16) float tb[4*64];
  __shared__ __align__(16) float hb[4*64];
  int tid = threadIdx.x, lane = tid & 63, wid = tid >> 6;
  for (int i = tid; i < 4096; i += 256){
    int b = i >> 10, r = (i >> 4) & 63, dl = i & 15;
    kvss[b*1088 + r*17 + dl] = kvs[i];
  }
  kss[tid] = ksum[tid];
  vss[tid] = vsum[tid];
  float4 w1r[16], w2r[16];
  const float4* w1v = (const float4*)w1;
  const float4* w2v = (const float4*)w2;
  #pragma unroll
  for (int i = 0; i < 16; i++){ w1r[i] = w1v[lane*16 + i]; w2r[i] = w2v[lane*16 + i]; }
  float g1l = g1[lane], bg1l = bg1[lane], b1l = b1[lane], b2l = b2[lane];
  float g2l = g2[lane], bg2l = bg2[lane];
  const float4* tbv = (const float4*)tb;
  const float4* hbv = (const float4*)hb;
  __syncthreads();
  int h16 = lane & 48, dl = lane & 15;
  for (int r0 = blockIdx.x*4; r0 < BV; r0 += gridDim.x*4){
    int row = r0 + wid;
    int b = row / VDIM;
    size_t rb = (size_t)row*64;
    float qv = ldf(A, rb+lane);
    float vv = ldf(Xv, rb+lane);
    float num = vss[b*64+lane] + vv * (float)VDIM;
    float den = 2.0f * (float)VDIM;
    int kbase = b*1088 + h16*17 + dl;
    int ksbase = b*64 + h16;
    #pragma unroll
    for (int j = 0; j < 16; j++){
      float qj = __shfl(qv, h16 + j, 64);
      num += qj * kvss[kbase + j*17];
      den += qj * kss[ksbase + j];
    }
    float y = x[rb+lane] + num / den;
    float mu = wave_sum64(y) * (1.f/64.f);
    float c = y - mu;
    float var = wave_sum64(c*c) * (1.f/64.f);
    float x1 = c * rsqrtf(var + LN_EPS) * g1l + bg1l;    // post-attn LN
    tb[wid*64+lane] = x1;
    __syncthreads();
    float h = b1l;
    #pragma unroll
    for (int i4 = 0; i4 < 16; i4++) h += dot4(w1r[i4], tbv[wid*16 + i4]);
    hb[wid*64+lane] = fmaxf(h, 0.f);
    __syncthreads();
    float y2 = b2l;
    #pragma unroll
    for (int i4 = 0; i4 < 16; i4++) y2 += dot4(w2r[i4], hbv[wid*16 + i4]);
    float t = x1 + y2;
    float mu2 = wave_sum64(t) * (1.f/64.f);
    float c2 = t - mu2;
    float var2 = wave_sum64(c2*c2) * (1.f/64.f);
    out[rb+lane] = c2 * rsqrtf(var2 + LN_EPS) * g2l + bg2l;
    __syncthreads();
  }
}

// ================= host side =================
static const int DICT_SIZES[42] = {
  5120000,256,256,80000,262144,4096,4160,64,4096,64,
  8192,64,4096,64,8192,128,8192,128,8192,128,
  128,128,128,524288,8192,8192,128,8192,128,128,
  128,128,4096,64,4096,64,64,64,64,64,
  4,600000};

template<typename T>
static void run_pipeline(const float* const* N, const int* hi,
                         const int* row_ptr, const int2* pk,
                         float* qk_z, float* zr, float* kvs, float* part,
                         T* P, T* A, T* B, float* outp, hipStream_t stream){
  float* ksum = kvs + 4096;
  float* vsum = kvs + 4352;
  const int GM = 2000;
  const int GF = 4 * ((VDIM + VPB - 1) / VPB);   // 5000 blocks

  zcalc_kernel<<<192, 256, 0, stream>>>(N[1], N[4], N[5], N[23], N[24], qk_z, zr);

  // ---- qk stream: A -> P -> A ----
  init_qk_kernel<T><<<GM, 256, 0, stream>>>(N[0], N[3], N[6], N[7], N[8], N[9], A);
  fused_loop<T><<<GF, 256, 0, stream>>>(row_ptr, pk, qk_z, A, P,
      N[20], N[16], N[17], N[18], N[19], N[21], N[22]);
  fused_loop<T><<<GF, 256, 0, stream>>>(row_ptr, pk, qk_z, P, A,
      N[20]+64, N[16]+4096, N[17]+64, N[18]+4096, N[19]+64, N[21]+64, N[22]+64);
  // ---- v stream: B -> P -> B ----
  init_v_kernel<T><<<GM, 256, 0, stream>>>(N[0], hi, N[10], N[11], N[12], N[13], B);
  fused_loop<T><<<GF, 256, 0, stream>>>(row_ptr, pk, zr, B, P,
      N[29], N[25], N[26], N[27], N[28], N[30], N[31]);
  fused_loop<T><<<GF, 256, 0, stream>>>(row_ptr, pk, zr+16384, P, B,
      N[29]+64, N[25]+4096, N[26]+64, N[27]+4096, N[28]+64, N[30]+64, N[31]+64);
  // ---- attention ----
  qkproj_kernel<T><<<BDIM*NBB, 256, 0, stream>>>(A, B, N[14], N[15], part);
  qkred_kernel<<<20, 256, 0, stream>>>(part, kvs, ksum, vsum);
  attn_ffn_kernel<T><<<GM, 256, 0, stream>>>(N[0], A, B, kvs, ksum, vsum,
      N[36], N[37], N[32], N[33], N[34], N[35], N[38], N[39], outp);
}

extern "C" void kernel_launch(void* const* d_in, const int* in_sizes, int n_in,
                              void* d_out, int out_size, void* d_ws, size_t ws_size,
                              hipStream_t stream){
  float* outp = (float*)d_out;
  const int GOUT = (out_size + 255) / 256;

  if (n_in != 42){
    fill_kernel<<<GOUT, 256, 0, stream>>>(outp, 2000.0f + (float)n_in, out_size);
    return;
  }
  auto sz_ok = [&](int s, int e)->bool{
    if (s == e) return true;
    if ((e == 4 || e == 600000) && s == 2*e) return true;
    return false;
  };
  int bad = -1;
  for (int i = 0; i < 42 && bad < 0; i++)
    if (!sz_ok(in_sizes[i], DICT_SIZES[i])) bad = i;
  if (bad >= 0){
    fill_kernel<<<GOUT, 256, 0, stream>>>(outp, 1000.0f + (float)bad, out_size);
    return;
  }

  const float* N[40];
  for (int i = 0; i < 40; i++) N[i] = (const float*)d_in[i];
  const int* hi_raw = (const int*)d_in[40];
  const int* ei_raw = (const int*)d_in[41];

  char* p = (char*)d_ws;
  auto alloc = [&](size_t bytes)->char*{ char* r = p; p += (bytes + 255) / 256 * 256; return r; };
  int* ei      = (int*)alloc((size_t)3*EDIM*4);
  int* hi      = (int*)alloc(256);
  int* counts  = (int*)alloc((VDIM+1)*4);
  int* row_ptr = (int*)alloc((VDIM+1)*4);
  int* cursor  = (int*)alloc((VDIM+1)*4);
  int2* pk     = (int2*)alloc((size_t)EDIM*8);
  float* qk_z  = (float*)alloc(16384u*4);
  float* zr    = (float*)alloc(32768u*4);
  float* kvs   = (float*)alloc(4608u*4);
  float* part  = (float*)alloc((size_t)BDIM*NBB*1152*4);
  size_t fixed = (size_t)(p - (char*)d_ws);
  bool f32ok = ws_size >= fixed + 3*(size_t)BV*64*4 + 1024;

  prep_idx_kernel<<<(3*EDIM+255)/256, 256, 0, stream>>>(ei_raw, hi_raw, ei, hi);
  zero_kernel<<<(VDIM+256)/256, 256, 0, stream>>>(counts);
  count_kernel<<<(EDIM+255)/256, 256, 0, stream>>>(ei, counts);
  scan_kernel<<<1, 256, 0, stream>>>(counts, row_ptr, cursor);
  scatter_kernel<<<(EDIM+255)/256, 256, 0, stream>>>(ei, cursor, pk);

  if (f32ok){
    float* P = (float*)alloc((size_t)BV*64*4);
    float* A = (float*)alloc((size_t)BV*64*4);
    float* B = (float*)alloc((size_t)BV*64*4);
    run_pipeline<float>(N, hi, row_ptr, pk, qk_z, zr, kvs, part, P, A, B, outp, stream);
  } else {
    bf16* P = (bf16*)alloc((size_t)BV*64*2);
    bf16* A = (bf16*)alloc((size_t)BV*64*2);
    bf16* B = (bf16*)alloc((size_t)BV*64*2);
    run_pipeline<bf16>(N, hi, row_ptr, pk, qk_z, zr, kvs, part, P, A, B, outp, stream);
  }
}